// Round 1
// baseline (1392.227 us; speedup 1.0000x reference)
//
#include <hip/hip_runtime.h>
#include <cmath>

#define ALPHA 0.8f
#define KAPPA 0.8f
#define THR   1.0f
#define NB    1000
#define NI    784
#define NR    256
#define NO    10

// ---------------------------------------------------------------------------
// Kernel 1: forward GEMM  v_new = ALPHA*v*(1-z) + z@w_rec_eff^T + x@w_in^T
// Fused epilogue: z_new, h, Faz_new.
// Tiled 64x64, K = 256 (z/w_rec) + 784 (x/w_in) = 1040, k-chunks of 16.
// ---------------------------------------------------------------------------
__global__ __launch_bounds__(256) void k_fwd(
    const float* __restrict__ x, const float* __restrict__ z,
    const float* __restrict__ w_in, const float* __restrict__ w_rec,
    const float* __restrict__ v, const float* __restrict__ Faz,
    float* __restrict__ z_new, float* __restrict__ h_out,
    float* __restrict__ Faz_new)
{
    __shared__ float AT[16][68];   // [k-local][b-local], pad 68 for bank spread
    __shared__ float BT[16][68];   // [k-local][i-local]
    const int t  = threadIdx.x;
    const int tx = t & 15, ty = t >> 4;
    const int b0 = blockIdx.x * 64, i0 = blockIdx.y * 64;
    const int lrow = t >> 2;            // 0..63
    const int lc4  = (t & 3) * 4;       // 0,4,8,12

    float acc[4][4] = {};

    for (int kc = 0; kc < 1040; kc += 16) {
        const int kk = kc + lc4;
        float4 av = make_float4(0.f, 0.f, 0.f, 0.f);
        const int bb = b0 + lrow;
        if (bb < NB) {
            if (kk < NR) av = *(const float4*)&z[bb * NR + kk];
            else         av = *(const float4*)&x[bb * NI + (kk - NR)];
        }
        float4 bv;
        {
            const int ii = i0 + lrow;
            if (kk < NR) bv = *(const float4*)&w_rec[ii * NR + kk];
            else         bv = *(const float4*)&w_in[ii * NI + (kk - NR)];
        }
        __syncthreads();
        AT[lc4 + 0][lrow] = av.x; AT[lc4 + 1][lrow] = av.y;
        AT[lc4 + 2][lrow] = av.z; AT[lc4 + 3][lrow] = av.w;
        BT[lc4 + 0][lrow] = bv.x; BT[lc4 + 1][lrow] = bv.y;
        BT[lc4 + 2][lrow] = bv.z; BT[lc4 + 3][lrow] = bv.w;
        __syncthreads();
        #pragma unroll
        for (int k = 0; k < 16; ++k) {
            float4 a4 = *(const float4*)&AT[k][4 * ty];
            float4 b4 = *(const float4*)&BT[k][4 * tx];
            const float ar[4] = {a4.x, a4.y, a4.z, a4.w};
            const float br[4] = {b4.x, b4.y, b4.z, b4.w};
            #pragma unroll
            for (int r = 0; r < 4; ++r)
                #pragma unroll
                for (int c = 0; c < 4; ++c)
                    acc[r][c] += ar[r] * br[c];
        }
    }

    // diagonal fix values for this thread's 4 columns
    float diag[4];
    #pragma unroll
    for (int c = 0; c < 4; ++c) {
        const int ii = i0 + 4 * tx + c;
        diag[c] = w_rec[ii * NR + ii];
    }

    #pragma unroll
    for (int r = 0; r < 4; ++r) {
        const int bb = b0 + 4 * ty + r;
        if (bb >= NB) continue;
        const int ii = i0 + 4 * tx;
        float4 v4 = *(const float4*)&v[bb * NR + ii];
        float4 z4 = *(const float4*)&z[bb * NR + ii];
        float4 f4 = *(const float4*)&Faz[bb * NR + ii];
        const float vv[4] = {v4.x, v4.y, v4.z, v4.w};
        const float zz[4] = {z4.x, z4.y, z4.z, z4.w};
        const float ff[4] = {f4.x, f4.y, f4.z, f4.w};
        float zn[4], hh[4], fz[4];
        #pragma unroll
        for (int c = 0; c < 4; ++c) {
            const float vn = ALPHA * vv[c] * (1.f - zz[c]) + acc[r][c]
                             - zz[c] * diag[c];
            zn[c] = (vn > THR) ? 1.f : 0.f;
            hh[c] = fmaxf(0.f, 1.f - fabsf(vn - THR));
            fz[c] = ALPHA * ff[c] + zz[c];
        }
        *(float4*)&z_new[bb * NR + ii]   = make_float4(zn[0], zn[1], zn[2], zn[3]);
        *(float4*)&h_out[bb * NR + ii]   = make_float4(hh[0], hh[1], hh[2], hh[3]);
        *(float4*)&Faz_new[bb * NR + ii] = make_float4(fz[0], fz[1], fz[2], fz[3]);
    }
}

// ---------------------------------------------------------------------------
// Kernel 2: head — vo_new, softmax(yo), err, L = err@w_out, Lh = L*h.
// One wave (64 threads) per batch row.
// ---------------------------------------------------------------------------
__global__ __launch_bounds__(64) void k_head(
    const float* __restrict__ yt, const float* __restrict__ w_out,
    const float* __restrict__ vo, const float* __restrict__ z_new,
    const float* __restrict__ h, float* __restrict__ yo_out,
    float* __restrict__ err_out, float* __restrict__ L_out,
    float* __restrict__ Lh_out)
{
    const int b = blockIdx.x;
    const int lane = threadIdx.x;

    float zv[4];
    #pragma unroll
    for (int q = 0; q < 4; ++q) zv[q] = z_new[b * NR + lane + 64 * q];

    float so[NO];
    #pragma unroll
    for (int o = 0; o < NO; ++o) {
        float p = 0.f;
        #pragma unroll
        for (int q = 0; q < 4; ++q)
            p += zv[q] * w_out[o * NR + lane + 64 * q];
        #pragma unroll
        for (int m = 32; m >= 1; m >>= 1) p += __shfl_xor(p, m, 64);
        so[o] = p;   // all lanes hold full sum
    }

    float e[NO], mx = -1e30f;
    #pragma unroll
    for (int o = 0; o < NO; ++o) {
        e[o] = KAPPA * vo[b * NO + o] + so[o];
        mx = fmaxf(mx, e[o]);
    }
    float s = 0.f;
    #pragma unroll
    for (int o = 0; o < NO; ++o) { e[o] = expf(e[o] - mx); s += e[o]; }
    const float inv = 1.f / s;
    float err[NO];
    #pragma unroll
    for (int o = 0; o < NO; ++o) {
        e[o] *= inv;                        // yo
        err[o] = e[o] - yt[b * NO + o];
    }
    if (lane == 0) {
        #pragma unroll
        for (int o = 0; o < NO; ++o) {
            yo_out[b * NO + o]  = e[o];
            err_out[b * NO + o] = err[o];
        }
    }
    #pragma unroll
    for (int q = 0; q < 4; ++q) {
        const int i = lane + 64 * q;
        float Lv = 0.f;
        #pragma unroll
        for (int o = 0; o < NO; ++o) Lv += err[o] * w_out[o * NR + i];
        L_out[b * NR + i]  = Lv;
        Lh_out[b * NR + i] = Lv * h[b * NR + i];
    }
}

// ---------------------------------------------------------------------------
// Kernel 3: Fax_new = ALPHA*Fax + x   (784000 floats)
// ---------------------------------------------------------------------------
__global__ void k_fax(const float* __restrict__ x, const float* __restrict__ Fax,
                      float* __restrict__ Fax_new)
{
    const int idx = blockIdx.x * blockDim.x + threadIdx.x;
    if (idx >= NB * NI / 4) return;
    float4 xv = ((const float4*)x)[idx];
    float4 fv = ((const float4*)Fax)[idx];
    float4 o;
    o.x = ALPHA * fv.x + xv.x; o.y = ALPHA * fv.y + xv.y;
    o.z = ALPHA * fv.z + xv.z; o.w = ALPHA * fv.w + xv.w;
    ((float4*)Fax_new)[idx] = o;
}

// ---------------------------------------------------------------------------
// Kernel 4: gw_out partials — part[s][o][i] = sum_{b in chunk s} err[b][o] *
//           (KAPPA*Fkz[b][i] + z_new[b][i])
// ---------------------------------------------------------------------------
__global__ __launch_bounds__(256) void k_gwout(
    const float* __restrict__ err, const float* __restrict__ Fkz,
    const float* __restrict__ z_new, float* __restrict__ part)
{
    const int s = blockIdx.x;      // 0..15
    const int o = blockIdx.y;      // 0..9
    const int i = threadIdx.x;     // 0..255
    const int b0 = s * 63, b1 = min(NB, b0 + 63);
    float acc = 0.f;
    for (int b = b0; b < b1; ++b)
        acc += err[b * NO + o] * (KAPPA * Fkz[b * NR + i] + z_new[b * NR + i]);
    part[(s * NO + o) * NR + i] = acc;
}

// ---------------------------------------------------------------------------
// Kernel 5: correction GEMM  C[i][j] = sum_b Lh[b][i] * Bm[b][j]
// (both operands K-major, K = 1000). 64x64 tiles.
// ---------------------------------------------------------------------------
template <int NJ>
__global__ __launch_bounds__(256) void k_corr(
    const float* __restrict__ A, const float* __restrict__ Bm,
    float* __restrict__ C)
{
    __shared__ float ATt[16][64];
    __shared__ float BTt[16][64];
    const int t  = threadIdx.x;
    const int tx = t & 15, ty = t >> 4;
    const int j0 = blockIdx.x * 64;
    const int i0 = blockIdx.y * 64;
    const int lrow = t >> 4;          // k-local 0..15
    const int lc4  = (t & 15) * 4;    // col 0..60

    float acc[4][4] = {};

    for (int kc = 0; kc < 1008; kc += 16) {
        const int kb = kc + lrow;
        float4 av = make_float4(0.f, 0.f, 0.f, 0.f);
        float4 bv = make_float4(0.f, 0.f, 0.f, 0.f);
        if (kb < NB) {
            av = *(const float4*)&A[kb * NR + i0 + lc4];
            if (j0 + lc4 + 3 < NJ)
                bv = *(const float4*)&Bm[kb * NJ + j0 + lc4];
        }
        __syncthreads();
        *(float4*)&ATt[lrow][lc4] = av;
        *(float4*)&BTt[lrow][lc4] = bv;
        __syncthreads();
        #pragma unroll
        for (int k = 0; k < 16; ++k) {
            float4 a4 = *(const float4*)&ATt[k][4 * ty];
            float4 b4 = *(const float4*)&BTt[k][4 * tx];
            const float ar[4] = {a4.x, a4.y, a4.z, a4.w};
            const float br[4] = {b4.x, b4.y, b4.z, b4.w};
            #pragma unroll
            for (int r = 0; r < 4; ++r)
                #pragma unroll
                for (int c = 0; c < 4; ++c)
                    acc[r][c] += ar[r] * br[c];
        }
    }
    const int j = j0 + 4 * tx;
    if (j + 3 < NJ) {
        #pragma unroll
        for (int r = 0; r < 4; ++r) {
            const int i = i0 + 4 * ty + r;
            *(float4*)&C[i * NJ + j] =
                make_float4(acc[r][0], acc[r][1], acc[r][2], acc[r][3]);
        }
    }
}

// ---------------------------------------------------------------------------
// Kernel 6: streaming einsum over Fke_in — part[s][i][j] = sum_{b in chunk}
//           L[b][i] * Fke_in[b][i][j].  One block per (i, b-split).
// ---------------------------------------------------------------------------
__global__ __launch_bounds__(256) void k_eins_in(
    const float* __restrict__ L, const float* __restrict__ Fke,
    float* __restrict__ part)
{
    const int i = blockIdx.x;      // 0..255
    const int s = blockIdx.y;      // 0..3
    const int t = threadIdx.x;
    if (t >= NI / 4) return;       // 196 active lanes
    const int b0 = s * 250;
    const float* __restrict__ base = Fke + ((size_t)(b0 * NR + i)) * NI + 4 * t;
    const float* __restrict__ Lp   = L + b0 * NR + i;
    float4 acc = make_float4(0.f, 0.f, 0.f, 0.f);
    #pragma unroll 4
    for (int it = 0; it < 250; ++it) {
        const float lb = *Lp;
        float4 f = *(const float4*)base;
        acc.x += lb * f.x; acc.y += lb * f.y;
        acc.z += lb * f.z; acc.w += lb * f.w;
        base += (size_t)NR * NI;
        Lp += NR;
    }
    *(float4*)&part[((size_t)(s * NR + i)) * NI + 4 * t] = acc;
}

// ---------------------------------------------------------------------------
// Kernel 7: streaming einsum over Fke_rec — block = (group of 4 i, b-split).
// ---------------------------------------------------------------------------
__global__ __launch_bounds__(256) void k_eins_rec(
    const float* __restrict__ L, const float* __restrict__ Fke,
    float* __restrict__ part)
{
    const int ig = blockIdx.x;     // 0..63
    const int s  = blockIdx.y;     // 0..15
    const int g    = threadIdx.x >> 6;   // 0..3 (one wave per i)
    const int lane = threadIdx.x & 63;
    const int i = ig * 4 + g;
    const int b0 = s * 63, b1 = min(NB, b0 + 63);
    float4 acc = make_float4(0.f, 0.f, 0.f, 0.f);
    #pragma unroll 4
    for (int b = b0; b < b1; ++b) {
        const float lb = L[b * NR + i];
        float4 f = *(const float4*)&Fke[((size_t)(b * NR + i)) * NR + 4 * lane];
        acc.x += lb * f.x; acc.y += lb * f.y;
        acc.z += lb * f.z; acc.w += lb * f.w;
    }
    *(float4*)&part[((size_t)(s * NR + i)) * NR + 4 * lane] = acc;
}

// ---------------------------------------------------------------------------
// Kernel 8a/b/c: final reductions  gw = KAPPA * sum_s part + corr
// ---------------------------------------------------------------------------
__global__ void k_red_in(const float* __restrict__ part,
                         const float* __restrict__ corr, float* __restrict__ out)
{
    const int idx = blockIdx.x * blockDim.x + threadIdx.x;
    if (idx >= NR * NI / 4) return;
    float4 a = make_float4(0.f, 0.f, 0.f, 0.f);
    #pragma unroll
    for (int s = 0; s < 4; ++s) {
        float4 p = ((const float4*)part)[(size_t)s * (NR * NI / 4) + idx];
        a.x += p.x; a.y += p.y; a.z += p.z; a.w += p.w;
    }
    float4 c = ((const float4*)corr)[idx];
    ((float4*)out)[idx] = make_float4(KAPPA * a.x + c.x, KAPPA * a.y + c.y,
                                      KAPPA * a.z + c.z, KAPPA * a.w + c.w);
}

__global__ void k_red_rec(const float* __restrict__ part,
                          const float* __restrict__ corr, float* __restrict__ out)
{
    const int idx = blockIdx.x * blockDim.x + threadIdx.x;
    if (idx >= NR * NR / 4) return;
    float4 a = make_float4(0.f, 0.f, 0.f, 0.f);
    #pragma unroll
    for (int s = 0; s < 16; ++s) {
        float4 p = ((const float4*)part)[(size_t)s * (NR * NR / 4) + idx];
        a.x += p.x; a.y += p.y; a.z += p.z; a.w += p.w;
    }
    float4 c = ((const float4*)corr)[idx];
    ((float4*)out)[idx] = make_float4(KAPPA * a.x + c.x, KAPPA * a.y + c.y,
                                      KAPPA * a.z + c.z, KAPPA * a.w + c.w);
}

__global__ void k_red_out(const float* __restrict__ part, float* __restrict__ out)
{
    const int idx = blockIdx.x * blockDim.x + threadIdx.x;
    if (idx >= NO * NR / 4) return;
    float4 a = make_float4(0.f, 0.f, 0.f, 0.f);
    #pragma unroll
    for (int s = 0; s < 16; ++s) {
        float4 p = ((const float4*)part)[(size_t)s * (NO * NR / 4) + idx];
        a.x += p.x; a.y += p.y; a.z += p.z; a.w += p.w;
    }
    ((float4*)out)[idx] = a;
}

// ---------------------------------------------------------------------------
extern "C" void kernel_launch(void* const* d_in, const int* in_sizes, int n_in,
                              void* d_out, int out_size, void* d_ws, size_t ws_size,
                              hipStream_t stream)
{
    const float* x       = (const float*)d_in[0];
    const float* yt      = (const float*)d_in[2];
    const float* w_in    = (const float*)d_in[3];
    const float* w_rec   = (const float*)d_in[4];
    const float* w_out   = (const float*)d_in[5];
    const float* v       = (const float*)d_in[6];
    const float* vo      = (const float*)d_in[7];
    const float* z       = (const float*)d_in[8];
    const float* Faz     = (const float*)d_in[9];
    const float* Fkz     = (const float*)d_in[10];
    const float* Fax     = (const float*)d_in[11];
    const float* Fke_rec = (const float*)d_in[12];
    const float* Fke_in  = (const float*)d_in[13];

    float* out    = (float*)d_out;
    float* yo     = out;                 // [1000,10]
    float* gw_in  = out + 10000;         // [256,784]
    float* gw_rec = out + 210704;        // [256,256]
    float* gw_out = out + 276240;        // [10,256]

    // workspace layout (floats) — total 4,232,592 floats ≈ 16.9 MB
    float* w        = (float*)d_ws;
    float* z_new    = w;                 // 256000
    float* h        = w + 256000;        // 256000
    float* Faz_new  = w + 512000;        // 256000
    float* L        = w + 768000;        // 256000
    float* Lh       = w + 1024000;       // 256000
    float* err      = w + 1280000;       // 10000
    float* Fax_new  = w + 1290000;       // 784000
    float* corr_rec = w + 2074000;       // 65536
    float* corr_in  = w + 2139536;       // 200704
    float* part_out = w + 2340240;       // 16*2560
    float* part_rec = w + 2381200;       // 16*65536
    float* part_in  = w + 3429776;       // 4*200704

    // 1. forward GEMM + spike/trace epilogue
    k_fwd<<<dim3(16, 4), 256, 0, stream>>>(x, z, w_in, w_rec, v, Faz,
                                           z_new, h, Faz_new);
    // 2. head: softmax, err, L, Lh
    k_head<<<dim3(NB), 64, 0, stream>>>(yt, w_out, vo, z_new, h,
                                        yo, err, L, Lh);
    // 3. Fax_new
    k_fax<<<dim3((NB * NI / 4 + 255) / 256), 256, 0, stream>>>(x, Fax, Fax_new);
    // 4. gw_out partials
    k_gwout<<<dim3(16, 10), 256, 0, stream>>>(err, Fkz, z_new, part_out);
    // 5. correction GEMMs
    k_corr<NR><<<dim3(4, 4), 256, 0, stream>>>(Lh, Faz_new, corr_rec);
    k_corr<NI><<<dim3(13, 4), 256, 0, stream>>>(Lh, Fax_new, corr_in);
    // 6/7. streaming einsums (the HBM-bound bulk)
    k_eins_in<<<dim3(256, 4), 256, 0, stream>>>(L, Fke_in, part_in);
    k_eins_rec<<<dim3(64, 16), 256, 0, stream>>>(L, Fke_rec, part_rec);
    // 8. final reductions
    k_red_in<<<dim3((NR * NI / 4 + 255) / 256), 256, 0, stream>>>(part_in, corr_in, gw_in);
    k_red_rec<<<dim3((NR * NR / 4 + 255) / 256), 256, 0, stream>>>(part_rec, corr_rec, gw_rec);
    k_red_out<<<dim3((NO * NR / 4 + 255) / 256), 256, 0, stream>>>(part_out, gw_out);
}